// Round 5
// baseline (205.879 us; speedup 1.0000x reference)
//
#include <hip/hip_runtime.h>
#include <hip/hip_bf16.h>

#define NSTEP 50
#define S51 51
#define HID 128
#define MT 64                  // rows per tile
#define BPB 8                  // batch elems per block (block owns them -> no global atomics)
#define RPB (BPB * S51)        // 408 valid rows per block
#define NTILE 7                // ceil(408/64): 448 rows, 40 masked
#define GRID (16384 / BPB)     // 2048 blocks
#define BLOCK 256              // 4 waves
#define B1S 20                 // B1 row stride in shorts (40B: 8B-aligned, 2-way banks = free)

typedef __attribute__((ext_vector_type(8))) short short8;
typedef __attribute__((ext_vector_type(4))) float floatx4;
typedef __attribute__((ext_vector_type(16))) float floatx16;

// Single-instruction packed f32->bf16 (v_cvt_pk_bf16_f32, gfx950). Fallback:
// manual RNE (no NaN path; values finite) + v_perm pack, ~5 VALU/pair.
__device__ __forceinline__ unsigned pk_bf16(float a, float b) {
#if __has_builtin(__builtin_amdgcn_cvt_pk_bf16_f32)
    typedef __bf16 bf16x2 __attribute__((ext_vector_type(2)));
    bf16x2 t = __builtin_amdgcn_cvt_pk_bf16_f32(a, b);   // D.lo = S0, D.hi = S1
    unsigned u;
    __builtin_memcpy(&u, &t, 4);
    return u;
#else
    unsigned ua = __float_as_uint(a), ub = __float_as_uint(b);
    ua = ua + 0x7fffu + ((ua >> 16) & 1u);
    ub = ub + 0x7fffu + ((ub >> 16) & 1u);
    return __builtin_amdgcn_perm(ub, ua, 0x07060302);    // [ua.hi16, ub.hi16]
#endif
}

// Swizzled activation layout: row-major 64x128 bf16, rows are 16 chunks of 16B,
// phys_chunk = chunk ^ (row & 15). Conflict-free for writers and B-operand readers.
__device__ __forceinline__ int sw_idx(int row, int chunk) {
    return row * HID + ((chunk ^ (row & 15)) << 3);   // in shorts
}

// 4 waves/block; wave wv owns hidden slice [wv*32, wv*32+32) as MFMA A-operand.
// L1 also via MFMA: B1 rows = [X, h, 1, 0...] (K=16), A-frag = [w1_row0, w1_row1, b1].
// Layer 4 fused into L3 accumulators. 2 barriers per tile.
__launch_bounds__(BLOCK, 4)
__global__ void monotonic_fused(const float* __restrict__ x, const float* __restrict__ h,
                                const float* __restrict__ w1, const float* __restrict__ b1,
                                const float* __restrict__ w2, const float* __restrict__ b2,
                                const float* __restrict__ w3, const float* __restrict__ b3,
                                const float* __restrict__ w4, const float* __restrict__ b4,
                                float* __restrict__ out) {
    __shared__ __align__(16) unsigned short A1[MT * HID];   // a1 (L1 out, L2 in), 16 KB
    __shared__ __align__(16) unsigned short A2[MT * HID];   // a2 (L2 out, L3 in), 16 KB
    __shared__ __align__(8)  unsigned short B1[2][MT * B1S];// L1 MFMA B-operand, 2x2.5 KB
    __shared__ float b2s[HID], b3s[HID], w4s[HID];
    __shared__ float fs[S51], ts[S51];
    __shared__ float xs[BPB], hs[BPB], osum[BPB];
    __shared__ float posum[MT];                              // per-row fused-L4 partials

    const int tid = threadIdx.x;
    const int lane = tid & 63;
    const int wv = tid >> 6;      // 0..3 = hidden 32-slice
    const int l31 = lane & 31;
    const int hi = lane >> 5;

    // ---- stage small tensors ----
    if (tid < HID) { b2s[tid] = b2[tid]; b3s[tid] = b3[tid]; w4s[tid] = w4[tid]; }
    if (tid < MT) posum[tid] = 0.0f;
    if (tid < BPB) {
        xs[tid] = x[blockIdx.x * BPB + tid];
        hs[tid] = h[blockIdx.x * BPB + tid];
        osum[tid] = 0.0f;
    }
    if (tid < S51) {
        // Faithful port of compute_cc_weights (verified R1-R4, absmax 0.031)
        const float PI50 = 0.06283185307179586f;  // pi/50
        float acc = 1.0f;
        for (int i = 2; i <= 50; i += 2) {
            int m = (i * tid) % 100;  // exact argument reduction
            acc += (2.0f / (1.0f - (float)(i * i))) * cosf((float)m * PI50);
        }
        float ccw = acc * 0.04f * ((tid == 0 || tid == NSTEP) ? 0.5f : 1.0f);
        fs[tid] = ccw * 0.5f;                               // folds the (x-x0)*0.5 factor
        ts[tid] = (cosf((float)tid * PI50) + 1.0f) * 0.5f;  // (steps+1)/2
    }
    const float b4v = b4[0];

    // ---- gather A-operand weight fragments (coalesced over l31) ----
    // w2f/w3f[kc] elem e = W[kc*16 + hi*8 + e][wv*32 + l31]
    short8 w2f[8], w3f[8], w1f;
    {
        const int irow = wv * 32 + l31;
#pragma unroll
        for (int kc = 0; kc < 8; ++kc) {
            const int kb = kc * 16 + hi * 8;
            union { short8 s; unsigned u[4]; } c2, c3;
#pragma unroll
            for (int e2 = 0; e2 < 4; ++e2) {
                c2.u[e2] = pk_bf16(w2[(kb + 2 * e2) * HID + irow], w2[(kb + 2 * e2 + 1) * HID + irow]);
                c3.u[e2] = pk_bf16(w3[(kb + 2 * e2) * HID + irow], w3[(kb + 2 * e2 + 1) * HID + irow]);
            }
            w2f[kc] = c2.s;
            w3f[kc] = c3.s;
        }
        union { short8 s; unsigned u[4]; } c1;
        if (hi == 0) {  // k=0: w1 row0, k=1: w1 row1, k=2: b1 (B supplies 1.0), k>=3: 0
            c1.u[0] = pk_bf16(w1[irow], w1[HID + irow]);
            c1.u[1] = pk_bf16(b1[irow], 0.0f);
            c1.u[2] = 0; c1.u[3] = 0;
        } else {
            c1.u[0] = 0; c1.u[1] = 0; c1.u[2] = 0; c1.u[3] = 0;
        }
        w1f = c1.s;
    }
    __syncthreads();

    // ---- build B1[0] for tile 0 ----
    if (tid < MT) {
        int lrc = tid;  // tile 0 rows all valid
        unsigned bbl = (unsigned)lrc / 51u;
        int ss = lrc - (int)bbl * 51;
        unsigned w0 = pk_bf16(xs[bbl] * ts[ss], hs[bbl]);
        unsigned short* p = &B1[0][tid * B1S];
        *(unsigned long long*)(p)     = (0x3F80ULL << 32) | (unsigned long long)w0;
        *(unsigned long long*)(p + 4) = 0ULL;
        *(unsigned long long*)(p + 8) = 0ULL;
        *(unsigned long long*)(p + 12) = 0ULL;
    }
    __syncthreads();

    // ---- L1-MFMA for tile 0 -> A1; build B1[1] for tile 1 ----
    {
        floatx16 d0 = {0.f,0.f,0.f,0.f,0.f,0.f,0.f,0.f,0.f,0.f,0.f,0.f,0.f,0.f,0.f,0.f};
        floatx16 d1 = d0;
        union { short8 s; unsigned long long q[2]; } f0, f1;
        const unsigned short* pb = &B1[0][0];
        f0.q[0] = *(const unsigned long long*)&pb[l31 * B1S + hi * 8];
        f0.q[1] = *(const unsigned long long*)&pb[l31 * B1S + hi * 8 + 4];
        f1.q[0] = *(const unsigned long long*)&pb[(l31 + 32) * B1S + hi * 8];
        f1.q[1] = *(const unsigned long long*)&pb[(l31 + 32) * B1S + hi * 8 + 4];
        d0 = __builtin_amdgcn_mfma_f32_32x32x16_bf16(w1f, f0.s, d0, 0, 0, 0);
        d1 = __builtin_amdgcn_mfma_f32_32x32x16_bf16(w1f, f1.s, d1, 0, 0, 0);
#pragma unroll
        for (int g = 0; g < 4; ++g) {
            const int chI = wv * 4 + g;
            float v0 = fmaxf(d0[4 * g + 0], 0.0f), v1 = fmaxf(d0[4 * g + 1], 0.0f);
            float v2 = fmaxf(d0[4 * g + 2], 0.0f), v3 = fmaxf(d0[4 * g + 3], 0.0f);
            *(unsigned long long*)(&A1[sw_idx(l31, chI) + 4 * hi]) =
                ((unsigned long long)pk_bf16(v2, v3) << 32) | (unsigned long long)pk_bf16(v0, v1);
            v0 = fmaxf(d1[4 * g + 0], 0.0f); v1 = fmaxf(d1[4 * g + 1], 0.0f);
            v2 = fmaxf(d1[4 * g + 2], 0.0f); v3 = fmaxf(d1[4 * g + 3], 0.0f);
            *(unsigned long long*)(&A1[sw_idx(l31 + 32, chI) + 4 * hi]) =
                ((unsigned long long)pk_bf16(v2, v3) << 32) | (unsigned long long)pk_bf16(v0, v1);
        }
        if (tid < MT) {
            int lr = MT + tid;  // tile 1
            int lrc = lr < RPB ? lr : RPB - 1;
            unsigned bbl = (unsigned)lrc / 51u;
            int ss = lrc - (int)bbl * 51;
            unsigned w0 = pk_bf16(xs[bbl] * ts[ss], hs[bbl]);
            unsigned short* p = &B1[1][tid * B1S];
            *(unsigned long long*)(p)     = (0x3F80ULL << 32) | (unsigned long long)w0;
            *(unsigned long long*)(p + 4) = 0ULL;
            *(unsigned long long*)(p + 8) = 0ULL;
            *(unsigned long long*)(p + 12) = 0ULL;
        }
    }
    __syncthreads();

    for (int t = 0; t < NTILE; ++t) {
        // ================= P1: layer 2 (read A1), bias pre-loaded in acc =================
        floatx16 a0, a1;
#pragma unroll
        for (int g = 0; g < 4; ++g) {
            const floatx4 bb = *(const floatx4*)(&b2s[wv * 32 + 8 * g + 4 * hi]);
#pragma unroll
            for (int rr = 0; rr < 4; ++rr) { a0[4 * g + rr] = bb[rr]; a1[4 * g + rr] = bb[rr]; }
        }
#pragma unroll
        for (int kc = 0; kc < 8; ++kc) {
            short8 f0 = *(const short8*)(&A1[sw_idx(l31, kc * 2 + hi)]);
            short8 f1 = *(const short8*)(&A1[sw_idx(l31 + 32, kc * 2 + hi)]);
            a0 = __builtin_amdgcn_mfma_f32_32x32x16_bf16(w2f[kc], f0, a0, 0, 0, 0);
            a1 = __builtin_amdgcn_mfma_f32_32x32x16_bf16(w2f[kc], f1, a1, 0, 0, 0);
        }
        // consume previous tile's fused-L4 partials while MFMAs drain
        if (t > 0 && tid < MT) {
            int lr = (t - 1) * MT + tid;
            float u = posum[tid] + b4v;
            posum[tid] = 0.0f;
            if (lr < RPB) {
                unsigned bbl = (unsigned)lr / 51u;
                int ss = lr - (int)bbl * 51;
                float dz = u > 0.0f ? u + 1.0f : __expf(u);  // elu(u)+1
                atomicAdd(&osum[bbl], dz * fs[ss]);
            }
        }
        // build B1[t&1] for tile t+2 (its last reader was P2(t-1), one barrier back)
        if (tid < MT && t + 2 < NTILE) {
            int lr = (t + 2) * MT + tid;
            int lrc = lr < RPB ? lr : RPB - 1;
            unsigned bbl = (unsigned)lrc / 51u;
            int ss = lrc - (int)bbl * 51;
            unsigned w0 = pk_bf16(xs[bbl] * ts[ss], hs[bbl]);
            unsigned short* p = &B1[t & 1][tid * B1S];
            *(unsigned long long*)(p)     = (0x3F80ULL << 32) | (unsigned long long)w0;
            *(unsigned long long*)(p + 4) = 0ULL;
            *(unsigned long long*)(p + 8) = 0ULL;
            *(unsigned long long*)(p + 12) = 0ULL;
        }
        // epilogue: relu(acc) -> A2 (bias already in acc)
#pragma unroll
        for (int g = 0; g < 4; ++g) {
            const int chI = wv * 4 + g;
            float v0 = fmaxf(a0[4 * g + 0], 0.0f), v1 = fmaxf(a0[4 * g + 1], 0.0f);
            float v2 = fmaxf(a0[4 * g + 2], 0.0f), v3 = fmaxf(a0[4 * g + 3], 0.0f);
            *(unsigned long long*)(&A2[sw_idx(l31, chI) + 4 * hi]) =
                ((unsigned long long)pk_bf16(v2, v3) << 32) | (unsigned long long)pk_bf16(v0, v1);
            v0 = fmaxf(a1[4 * g + 0], 0.0f); v1 = fmaxf(a1[4 * g + 1], 0.0f);
            v2 = fmaxf(a1[4 * g + 2], 0.0f); v3 = fmaxf(a1[4 * g + 3], 0.0f);
            *(unsigned long long*)(&A2[sw_idx(l31 + 32, chI) + 4 * hi]) =
                ((unsigned long long)pk_bf16(v2, v3) << 32) | (unsigned long long)pk_bf16(v0, v1);
        }
        __syncthreads();

        // ====== P2: layer 3 (read A2) + fused layer 4 + L1-MFMA(t+1) -> A1 ======
        floatx16 c0, c1;
#pragma unroll
        for (int g = 0; g < 4; ++g) {
            const floatx4 bb = *(const floatx4*)(&b3s[wv * 32 + 8 * g + 4 * hi]);
#pragma unroll
            for (int rr = 0; rr < 4; ++rr) { c0[4 * g + rr] = bb[rr]; c1[4 * g + rr] = bb[rr]; }
        }
#pragma unroll
        for (int kc = 0; kc < 8; ++kc) {
            short8 f0 = *(const short8*)(&A2[sw_idx(l31, kc * 2 + hi)]);
            short8 f1 = *(const short8*)(&A2[sw_idx(l31 + 32, kc * 2 + hi)]);
            c0 = __builtin_amdgcn_mfma_f32_32x32x16_bf16(w3f[kc], f0, c0, 0, 0, 0);
            c1 = __builtin_amdgcn_mfma_f32_32x32x16_bf16(w3f[kc], f1, c1, 0, 0, 0);
        }
        // fused layer 4: p[j] += sum_i relu(a3[i][j]) * w4[i] (bias pre-added in acc)
        {
            float p0 = 0.0f, p1 = 0.0f;
#pragma unroll
            for (int g = 0; g < 4; ++g) {
                const floatx4 w4v = *(const floatx4*)(&w4s[wv * 32 + 8 * g + 4 * hi]);
#pragma unroll
                for (int rr = 0; rr < 4; ++rr) {
                    p0 = fmaf(fmaxf(c0[4 * g + rr], 0.0f), w4v[rr], p0);
                    p1 = fmaf(fmaxf(c1[4 * g + rr], 0.0f), w4v[rr], p1);
                }
            }
            p0 += __shfl_xor(p0, 32);
            p1 += __shfl_xor(p1, 32);
            if (hi == 0) {
                atomicAdd(&posum[l31], p0);
                atomicAdd(&posum[l31 + 32], p1);
            }
        }
        // L1-MFMA for tile t+1 (reads B1[(t+1)&1], writes A1 for next P1)
        if (t + 1 < NTILE) {
            floatx16 d0 = {0.f,0.f,0.f,0.f,0.f,0.f,0.f,0.f,0.f,0.f,0.f,0.f,0.f,0.f,0.f,0.f};
            floatx16 d1 = d0;
            union { short8 s; unsigned long long q[2]; } f0, f1;
            const unsigned short* pb = &B1[(t + 1) & 1][0];
            f0.q[0] = *(const unsigned long long*)&pb[l31 * B1S + hi * 8];
            f0.q[1] = *(const unsigned long long*)&pb[l31 * B1S + hi * 8 + 4];
            f1.q[0] = *(const unsigned long long*)&pb[(l31 + 32) * B1S + hi * 8];
            f1.q[1] = *(const unsigned long long*)&pb[(l31 + 32) * B1S + hi * 8 + 4];
            d0 = __builtin_amdgcn_mfma_f32_32x32x16_bf16(w1f, f0.s, d0, 0, 0, 0);
            d1 = __builtin_amdgcn_mfma_f32_32x32x16_bf16(w1f, f1.s, d1, 0, 0, 0);
#pragma unroll
            for (int g = 0; g < 4; ++g) {
                const int chI = wv * 4 + g;
                float v0 = fmaxf(d0[4 * g + 0], 0.0f), v1 = fmaxf(d0[4 * g + 1], 0.0f);
                float v2 = fmaxf(d0[4 * g + 2], 0.0f), v3 = fmaxf(d0[4 * g + 3], 0.0f);
                *(unsigned long long*)(&A1[sw_idx(l31, chI) + 4 * hi]) =
                    ((unsigned long long)pk_bf16(v2, v3) << 32) | (unsigned long long)pk_bf16(v0, v1);
                v0 = fmaxf(d1[4 * g + 0], 0.0f); v1 = fmaxf(d1[4 * g + 1], 0.0f);
                v2 = fmaxf(d1[4 * g + 2], 0.0f); v3 = fmaxf(d1[4 * g + 3], 0.0f);
                *(unsigned long long*)(&A1[sw_idx(l31 + 32, chI) + 4 * hi]) =
                    ((unsigned long long)pk_bf16(v2, v3) << 32) | (unsigned long long)pk_bf16(v0, v1);
            }
        }
        __syncthreads();
    }

    // final consume of last tile's partials
    if (tid < MT) {
        int lr = (NTILE - 1) * MT + tid;
        if (lr < RPB) {
            float u = posum[tid] + b4v;
            unsigned bbl = (unsigned)lr / 51u;
            int ss = lr - (int)bbl * 51;
            float dz = u > 0.0f ? u + 1.0f : __expf(u);
            atomicAdd(&osum[bbl], dz * fs[ss]);
        }
    }
    __syncthreads();

    if (tid < BPB) out[blockIdx.x * BPB + tid] = hs[tid] + osum[tid] * xs[tid];
}

extern "C" void kernel_launch(void* const* d_in, const int* in_sizes, int n_in,
                              void* d_out, int out_size, void* d_ws, size_t ws_size,
                              hipStream_t stream) {
    const float* x  = (const float*)d_in[0];
    const float* h  = (const float*)d_in[1];
    const float* w1 = (const float*)d_in[2];
    const float* b1 = (const float*)d_in[3];
    const float* w2 = (const float*)d_in[4];
    const float* b2 = (const float*)d_in[5];
    const float* w3 = (const float*)d_in[6];
    const float* b3 = (const float*)d_in[7];
    const float* w4 = (const float*)d_in[8];
    const float* b4 = (const float*)d_in[9];
    float* out = (float*)d_out;

    monotonic_fused<<<GRID, BLOCK, 0, stream>>>(x, h, w1, b1, w2, b2, w3, b3, w4, b4, out);
}

// Round 6
// 178.473 us; speedup vs baseline: 1.1536x; 1.1536x over previous
//
#include <hip/hip_runtime.h>
#include <hip/hip_bf16.h>

#define NSTEP 50
#define S51 51
#define HID 128
#define MT 64                  // rows per tile
#define BPB 8                  // batch elems per block (block owns them -> no global atomics)
#define RPB (BPB * S51)        // 408 valid rows per block
#define NTILE 7                // ceil(408/64): 448 rows, 40 masked
#define GRID (16384 / BPB)     // 2048 blocks
#define BLOCK 256              // 4 waves

typedef __attribute__((ext_vector_type(8))) short short8;
typedef __attribute__((ext_vector_type(4))) float floatx4;
typedef __attribute__((ext_vector_type(16))) float floatx16;

// Single-instruction packed f32->bf16 (v_cvt_pk_bf16_f32, gfx950). Fallback:
// manual RNE (values finite, no NaN path) + v_perm pack, ~5 VALU/pair.
// Numerics validated in R5 (absmax 0.03125, unchanged).
__device__ __forceinline__ unsigned pk_bf16(float a, float b) {
#if __has_builtin(__builtin_amdgcn_cvt_pk_bf16_f32)
    typedef __bf16 bf16x2 __attribute__((ext_vector_type(2)));
    bf16x2 t = __builtin_amdgcn_cvt_pk_bf16_f32(a, b);   // D.lo = S0, D.hi = S1
    unsigned u;
    __builtin_memcpy(&u, &t, 4);
    return u;
#else
    unsigned ua = __float_as_uint(a), ub = __float_as_uint(b);
    ua = ua + 0x7fffu + ((ua >> 16) & 1u);
    ub = ub + 0x7fffu + ((ub >> 16) & 1u);
    return __builtin_amdgcn_perm(ub, ua, 0x07060302);    // [ua.hi16, ub.hi16]
#endif
}

// Swizzled activation layout: row-major 64x128 bf16, rows are 16 chunks of 16B,
// phys_chunk = chunk ^ (row & 15). No padding (A1+A2 = 32 KB), conflict-free for
// both the row-parallel writers and the MFMA B-operand readers.
__device__ __forceinline__ int sw_idx(int row, int chunk) {
    return row * HID + ((chunk ^ (row & 15)) << 3);   // in shorts
}

// R4 structure (known spill-free; R5's L1-MFMA variant spilled to scratch:
// 139 MB WRITE_SIZE). 4 waves/block; wave wv owns hidden slice [wv*32, wv*32+32)
// as MFMA A-operand (W^T in registers, 8 frags x 4 VGPR x 2 layers = 64 VGPR).
// Layer 4 fused into L3 accumulators. 2 barriers per tile.
__launch_bounds__(BLOCK, 4)
__global__ void monotonic_fused(const float* __restrict__ x, const float* __restrict__ h,
                                const float* __restrict__ w1, const float* __restrict__ b1,
                                const float* __restrict__ w2, const float* __restrict__ b2,
                                const float* __restrict__ w3, const float* __restrict__ b3,
                                const float* __restrict__ w4, const float* __restrict__ b4,
                                float* __restrict__ out) {
    __shared__ __align__(16) unsigned short A1[MT * HID];   // a1 (L1 out, L2 in), 16 KB
    __shared__ __align__(16) unsigned short A2[MT * HID];   // a2 (L2 out, L3 in), 16 KB
    __shared__ float w1s[2 * HID], b1s[HID], b2s[HID], b3s[HID], w4s[HID];
    __shared__ float fs[S51], ts[S51];
    __shared__ float xs[BPB], hs[BPB], osum[BPB];
    __shared__ float posum[MT];                              // per-row fused-L4 partials

    const int tid = threadIdx.x;
    const int lane = tid & 63;
    const int wv = tid >> 6;      // 0..3 = hidden 32-slice
    const int l31 = lane & 31;
    const int hi = lane >> 5;
    const int r1 = tid >> 2;          // L1 writer: row 0..63
    const int cb = (tid & 3) * 4;     // L1 writer: base chunk (4 chunks = 32 k-cols)

    // ---- stage small tensors ----
    w1s[tid] = w1[tid];               // 256 threads = 256 elems exactly
    if (tid < HID) {
        b1s[tid] = b1[tid]; b2s[tid] = b2[tid]; b3s[tid] = b3[tid]; w4s[tid] = w4[tid];
    }
    if (tid < MT) posum[tid] = 0.0f;
    if (tid < BPB) {
        xs[tid] = x[blockIdx.x * BPB + tid];
        hs[tid] = h[blockIdx.x * BPB + tid];
        osum[tid] = 0.0f;
    }
    if (tid < S51) {
        // Faithful port of compute_cc_weights (verified R1-R5, absmax 0.031)
        const float PI50 = 0.06283185307179586f;  // pi/50
        float acc = 1.0f;
        for (int i = 2; i <= 50; i += 2) {
            int m = (i * tid) % 100;  // exact argument reduction
            acc += (2.0f / (1.0f - (float)(i * i))) * cosf((float)m * PI50);
        }
        float ccw = acc * 0.04f * ((tid == 0 || tid == NSTEP) ? 0.5f : 1.0f);
        fs[tid] = ccw * 0.5f;                               // folds the (x-x0)*0.5 factor
        ts[tid] = (cosf((float)tid * PI50) + 1.0f) * 0.5f;  // (steps+1)/2
    }
    const float b4v = b4[0];

    // ---- gather W2^T / W3^T A-operand fragments (coalesced over l31) ----
    // frag[kc] elem e = W[kc*16 + hi*8 + e][wv*32 + l31]
    short8 w2f[8], w3f[8];
    {
        const int irow = wv * 32 + l31;
#pragma unroll
        for (int kc = 0; kc < 8; ++kc) {
            const int kb = kc * 16 + hi * 8;
            union { short8 s; unsigned u[4]; } c2, c3;
#pragma unroll
            for (int e2 = 0; e2 < 4; ++e2) {
                c2.u[e2] = pk_bf16(w2[(kb + 2 * e2) * HID + irow], w2[(kb + 2 * e2 + 1) * HID + irow]);
                c3.u[e2] = pk_bf16(w3[(kb + 2 * e2) * HID + irow], w3[(kb + 2 * e2 + 1) * HID + irow]);
            }
            w2f[kc] = c2.s;
            w3f[kc] = c3.s;
        }
    }
    __syncthreads();

    // ---- L1 for tile 0 -> A1 ----
    {
        int lrc = r1;  // tile 0 rows all valid
        unsigned bbl = (unsigned)lrc / 51u;
        int ss = lrc - (int)bbl * 51;
        float X = xs[bbl] * ts[ss], hb = hs[bbl];
#pragma unroll
        for (int cc = 0; cc < 4; ++cc) {
            const int kc0 = (cb + cc) * 8;
            unsigned vv[4];
#pragma unroll
            for (int e2 = 0; e2 < 4; ++e2) {
                float u0 = fmaxf(fmaf(X, w1s[kc0 + 2 * e2], fmaf(hb, w1s[HID + kc0 + 2 * e2], b1s[kc0 + 2 * e2])), 0.0f);
                float u1 = fmaxf(fmaf(X, w1s[kc0 + 2 * e2 + 1], fmaf(hb, w1s[HID + kc0 + 2 * e2 + 1], b1s[kc0 + 2 * e2 + 1])), 0.0f);
                vv[e2] = pk_bf16(u0, u1);
            }
            *(uint4*)(&A1[sw_idx(r1, cb + cc)]) = make_uint4(vv[0], vv[1], vv[2], vv[3]);
        }
    }
    __syncthreads();

    for (int t = 0; t < NTILE; ++t) {
        // ================= P1: layer 2 (read A1), bias pre-loaded in acc =================
        floatx16 a0, a1;
#pragma unroll
        for (int g = 0; g < 4; ++g) {
            const floatx4 bb = *(const floatx4*)(&b2s[wv * 32 + 8 * g + 4 * hi]);
#pragma unroll
            for (int rr = 0; rr < 4; ++rr) { a0[4 * g + rr] = bb[rr]; a1[4 * g + rr] = bb[rr]; }
        }
#pragma unroll
        for (int kc = 0; kc < 8; ++kc) {
            short8 f0 = *(const short8*)(&A1[sw_idx(l31, kc * 2 + hi)]);
            short8 f1 = *(const short8*)(&A1[sw_idx(l31 + 32, kc * 2 + hi)]);
            a0 = __builtin_amdgcn_mfma_f32_32x32x16_bf16(w2f[kc], f0, a0, 0, 0, 0);
            a1 = __builtin_amdgcn_mfma_f32_32x32x16_bf16(w2f[kc], f1, a1, 0, 0, 0);
        }
        // consume previous tile's fused-L4 partials while MFMAs drain
        if (t > 0 && tid < MT) {
            int lr = (t - 1) * MT + tid;
            float u = posum[tid] + b4v;
            posum[tid] = 0.0f;
            if (lr < RPB) {
                unsigned bbl = (unsigned)lr / 51u;
                int ss = lr - (int)bbl * 51;
                float dz = u > 0.0f ? u + 1.0f : __expf(u);  // elu(u)+1
                atomicAdd(&osum[bbl], dz * fs[ss]);
            }
        }
        // epilogue: relu(acc) -> A2 (bias already in acc)
#pragma unroll
        for (int g = 0; g < 4; ++g) {
            const int chI = wv * 4 + g;
            float v0 = fmaxf(a0[4 * g + 0], 0.0f), v1 = fmaxf(a0[4 * g + 1], 0.0f);
            float v2 = fmaxf(a0[4 * g + 2], 0.0f), v3 = fmaxf(a0[4 * g + 3], 0.0f);
            *(unsigned long long*)(&A2[sw_idx(l31, chI) + 4 * hi]) =
                ((unsigned long long)pk_bf16(v2, v3) << 32) | (unsigned long long)pk_bf16(v0, v1);
            v0 = fmaxf(a1[4 * g + 0], 0.0f); v1 = fmaxf(a1[4 * g + 1], 0.0f);
            v2 = fmaxf(a1[4 * g + 2], 0.0f); v3 = fmaxf(a1[4 * g + 3], 0.0f);
            *(unsigned long long*)(&A2[sw_idx(l31 + 32, chI) + 4 * hi]) =
                ((unsigned long long)pk_bf16(v2, v3) << 32) | (unsigned long long)pk_bf16(v0, v1);
        }
        __syncthreads();

        // ================= P2: layer 3 (read A2) + fused layer 4 + L1(t+1) =================
        floatx16 c0, c1;
#pragma unroll
        for (int g = 0; g < 4; ++g) {
            const floatx4 bb = *(const floatx4*)(&b3s[wv * 32 + 8 * g + 4 * hi]);
#pragma unroll
            for (int rr = 0; rr < 4; ++rr) { c0[4 * g + rr] = bb[rr]; c1[4 * g + rr] = bb[rr]; }
        }
#pragma unroll
        for (int kc = 0; kc < 8; ++kc) {
            short8 f0 = *(const short8*)(&A2[sw_idx(l31, kc * 2 + hi)]);
            short8 f1 = *(const short8*)(&A2[sw_idx(l31 + 32, kc * 2 + hi)]);
            c0 = __builtin_amdgcn_mfma_f32_32x32x16_bf16(w3f[kc], f0, c0, 0, 0, 0);
            c1 = __builtin_amdgcn_mfma_f32_32x32x16_bf16(w3f[kc], f1, c1, 0, 0, 0);
        }
        // fused layer 4: p[j] += sum_i relu(a3[i][j]) * w4[i] (bias pre-added in acc)
        {
            float p0 = 0.0f, p1 = 0.0f;
#pragma unroll
            for (int g = 0; g < 4; ++g) {
                const floatx4 w4v = *(const floatx4*)(&w4s[wv * 32 + 8 * g + 4 * hi]);
#pragma unroll
                for (int rr = 0; rr < 4; ++rr) {
                    p0 = fmaf(fmaxf(c0[4 * g + rr], 0.0f), w4v[rr], p0);
                    p1 = fmaf(fmaxf(c1[4 * g + rr], 0.0f), w4v[rr], p1);
                }
            }
            p0 += __shfl_xor(p0, 32);
            p1 += __shfl_xor(p1, 32);
            if (hi == 0) {
                atomicAdd(&posum[l31], p0);
                atomicAdd(&posum[l31 + 32], p1);
            }
        }
        // L1 for tile t+1 -> A1 (A1[t] fully consumed by P1's MFMAs before the barrier)
        if (t + 1 < NTILE) {
            int lr = (t + 1) * MT + r1;
            int lrc = lr < RPB ? lr : RPB - 1;
            unsigned bbl = (unsigned)lrc / 51u;
            int ss = lrc - (int)bbl * 51;
            float X = xs[bbl] * ts[ss], hb = hs[bbl];
#pragma unroll
            for (int cc = 0; cc < 4; ++cc) {
                const int kc0 = (cb + cc) * 8;
                unsigned vv[4];
#pragma unroll
                for (int e2 = 0; e2 < 4; ++e2) {
                    float u0 = fmaxf(fmaf(X, w1s[kc0 + 2 * e2], fmaf(hb, w1s[HID + kc0 + 2 * e2], b1s[kc0 + 2 * e2])), 0.0f);
                    float u1 = fmaxf(fmaf(X, w1s[kc0 + 2 * e2 + 1], fmaf(hb, w1s[HID + kc0 + 2 * e2 + 1], b1s[kc0 + 2 * e2 + 1])), 0.0f);
                    vv[e2] = pk_bf16(u0, u1);
                }
                *(uint4*)(&A1[sw_idx(r1, cb + cc)]) = make_uint4(vv[0], vv[1], vv[2], vv[3]);
            }
        }
        __syncthreads();
    }

    // final consume of last tile's partials
    if (tid < MT) {
        int lr = (NTILE - 1) * MT + tid;
        if (lr < RPB) {
            float u = posum[tid] + b4v;
            unsigned bbl = (unsigned)lr / 51u;
            int ss = lr - (int)bbl * 51;
            float dz = u > 0.0f ? u + 1.0f : __expf(u);
            atomicAdd(&osum[bbl], dz * fs[ss]);
        }
    }
    __syncthreads();

    if (tid < BPB) out[blockIdx.x * BPB + tid] = hs[tid] + osum[tid] * xs[tid];
}

extern "C" void kernel_launch(void* const* d_in, const int* in_sizes, int n_in,
                              void* d_out, int out_size, void* d_ws, size_t ws_size,
                              hipStream_t stream) {
    const float* x  = (const float*)d_in[0];
    const float* h  = (const float*)d_in[1];
    const float* w1 = (const float*)d_in[2];
    const float* b1 = (const float*)d_in[3];
    const float* w2 = (const float*)d_in[4];
    const float* b2 = (const float*)d_in[5];
    const float* w3 = (const float*)d_in[6];
    const float* b3 = (const float*)d_in[7];
    const float* w4 = (const float*)d_in[8];
    const float* b4 = (const float*)d_in[9];
    float* out = (float*)d_out;

    monotonic_fused<<<GRID, BLOCK, 0, stream>>>(x, h, w1, b1, w2, b2, w3, b3, w4, b4, out);
}

// Round 7
// 172.017 us; speedup vs baseline: 1.1969x; 1.0375x over previous
//
#include <hip/hip_runtime.h>
#include <hip/hip_bf16.h>

#define NSTEP 50
#define S51 51
#define HID 128
#define MT 64                  // rows per tile
#define BPB 16                 // batch elems per block (block owns them -> no global atomics)
#define RPB (BPB * S51)        // 816 valid rows per block
#define NTILE 13               // ceil(816/64): 832 rows, 16 masked (1.9% waste)
#define GRID (16384 / BPB)     // 1024 blocks = exactly 4 per CU, all resident
#define BLOCK 256              // 4 waves

typedef __attribute__((ext_vector_type(8))) short short8;
typedef __attribute__((ext_vector_type(4))) float floatx4;
typedef __attribute__((ext_vector_type(16))) float floatx16;

// f32 pair -> packed bf16 (lowers to v_cvt_pk_bf16_f32 on gfx950; verified R5/R6)
__device__ __forceinline__ unsigned pk_bf16(float a, float b) {
#if __has_builtin(__builtin_amdgcn_cvt_pk_bf16_f32)
    typedef __bf16 bf16x2 __attribute__((ext_vector_type(2)));
    bf16x2 t = __builtin_amdgcn_cvt_pk_bf16_f32(a, b);   // D.lo = S0, D.hi = S1
    unsigned u;
    __builtin_memcpy(&u, &t, 4);
    return u;
#else
    unsigned ua = __float_as_uint(a), ub = __float_as_uint(b);
    ua = ua + 0x7fffu + ((ua >> 16) & 1u);
    ub = ub + 0x7fffu + ((ub >> 16) & 1u);
    return __builtin_amdgcn_perm(ub, ua, 0x07060302);    // [ua.hi16, ub.hi16]
#endif
}

// Swizzled activation layout: row-major 64x128 bf16, rows = 16 chunks of 16B,
// phys_chunk = chunk ^ (row & 15). Conflict-minimal (R4: 9.2e6 vs padded R2: 3.6e7).
__device__ __forceinline__ int sw_idx(int row, int chunk) {
    return row * HID + ((chunk ^ (row & 15)) << 3);   // in shorts
}

// R4/R6 structure (spill-free baseline) + 3 VALU deletions:
//  (1) bias enters as MFMA C-operand of the peeled kc=0 MFMA (no acc-init movs)
//  (2) rowmap LUT replaces div-by-51 chains
//  (3) BPB=16 -> 1024 all-resident blocks, 1.9% masking waste
__launch_bounds__(BLOCK, 4)
__global__ void monotonic_fused(const float* __restrict__ x, const float* __restrict__ h,
                                const float* __restrict__ w1, const float* __restrict__ b1,
                                const float* __restrict__ w2, const float* __restrict__ b2,
                                const float* __restrict__ w3, const float* __restrict__ b3,
                                const float* __restrict__ w4, const float* __restrict__ b4,
                                float* __restrict__ out) {
    __shared__ __align__(16) unsigned short A1[MT * HID];   // a1 (L1 out, L2 in), 16 KB
    __shared__ __align__(16) unsigned short A2[MT * HID];   // a2 (L2 out, L3 in), 16 KB
    __shared__ float w1s[2 * HID], b1s[HID], b2s[HID], b3s[HID], w4s[HID];
    __shared__ float fs[S51], ts[S51];
    __shared__ float xs[BPB], hs[BPB], osum[BPB];
    __shared__ float posum[MT];                              // per-row fused-L4 partials
    __shared__ unsigned short rowmap[NTILE * MT];            // (bbl<<6)|ss per row

    const int tid = threadIdx.x;
    const int lane = tid & 63;
    const int wv = tid >> 6;      // 0..3 = hidden 32-slice
    const int l31 = lane & 31;
    const int hi = lane >> 5;
    const int r1 = tid >> 2;          // L1 writer: row 0..63
    const int cb = (tid & 3) * 4;     // L1 writer: base chunk (4 chunks = 32 k-cols)

    // ---- stage small tensors ----
    w1s[tid] = w1[tid];               // 256 threads = 256 elems exactly
    if (tid < HID) {
        b1s[tid] = b1[tid]; b2s[tid] = b2[tid]; b3s[tid] = b3[tid]; w4s[tid] = w4[tid];
    }
    if (tid < MT) posum[tid] = 0.0f;
    if (tid < BPB) {
        xs[tid] = x[blockIdx.x * BPB + tid];
        hs[tid] = h[blockIdx.x * BPB + tid];
        osum[tid] = 0.0f;
    }
    for (int i = tid; i < NTILE * MT; i += BLOCK) {
        int lrc = i < RPB ? i : RPB - 1;
        unsigned bbl = (unsigned)lrc / 51u;
        int ss = lrc - (int)bbl * 51;
        rowmap[i] = (unsigned short)((bbl << 6) | ss);
    }
    if (tid < S51) {
        // Faithful port of compute_cc_weights (verified R1-R6, absmax 0.031)
        const float PI50 = 0.06283185307179586f;  // pi/50
        float acc = 1.0f;
        for (int i = 2; i <= 50; i += 2) {
            int m = (i * tid) % 100;  // exact argument reduction
            acc += (2.0f / (1.0f - (float)(i * i))) * cosf((float)m * PI50);
        }
        float ccw = acc * 0.04f * ((tid == 0 || tid == NSTEP) ? 0.5f : 1.0f);
        fs[tid] = ccw * 0.5f;                               // folds the (x-x0)*0.5 factor
        ts[tid] = (cosf((float)tid * PI50) + 1.0f) * 0.5f;  // (steps+1)/2
    }
    const float b4v = b4[0];

    // ---- gather W2^T / W3^T A-operand fragments (coalesced over l31) ----
    // frag[kc] elem e = W[kc*16 + hi*8 + e][wv*32 + l31]
    short8 w2f[8], w3f[8];
    {
        const int irow = wv * 32 + l31;
#pragma unroll
        for (int kc = 0; kc < 8; ++kc) {
            const int kb = kc * 16 + hi * 8;
            union { short8 s; unsigned u[4]; } c2, c3;
#pragma unroll
            for (int e2 = 0; e2 < 4; ++e2) {
                c2.u[e2] = pk_bf16(w2[(kb + 2 * e2) * HID + irow], w2[(kb + 2 * e2 + 1) * HID + irow]);
                c3.u[e2] = pk_bf16(w3[(kb + 2 * e2) * HID + irow], w3[(kb + 2 * e2 + 1) * HID + irow]);
            }
            w2f[kc] = c2.s;
            w3f[kc] = c3.s;
        }
    }
    __syncthreads();

    // ---- L1 for tile 0 -> A1 ----
    {
        unsigned mm = rowmap[r1];
        unsigned bbl = mm >> 6;
        int ss = mm & 63;
        float X = xs[bbl] * ts[ss], hb = hs[bbl];
#pragma unroll
        for (int cc = 0; cc < 4; ++cc) {
            const int kc0 = (cb + cc) * 8;
            unsigned vv[4];
#pragma unroll
            for (int e2 = 0; e2 < 4; ++e2) {
                float u0 = fmaxf(fmaf(X, w1s[kc0 + 2 * e2], fmaf(hb, w1s[HID + kc0 + 2 * e2], b1s[kc0 + 2 * e2])), 0.0f);
                float u1 = fmaxf(fmaf(X, w1s[kc0 + 2 * e2 + 1], fmaf(hb, w1s[HID + kc0 + 2 * e2 + 1], b1s[kc0 + 2 * e2 + 1])), 0.0f);
                vv[e2] = pk_bf16(u0, u1);
            }
            *(uint4*)(&A1[sw_idx(r1, cb + cc)]) = make_uint4(vv[0], vv[1], vv[2], vv[3]);
        }
    }
    __syncthreads();

    for (int t = 0; t < NTILE; ++t) {
        // ======== P1: layer 2 (read A1); bias enters as C of the peeled MFMA ========
        floatx16 a0, a1;
        {
            union { floatx16 v; floatx4 q[4]; } ci;
#pragma unroll
            for (int g = 0; g < 4; ++g) ci.q[g] = *(const floatx4*)(&b2s[wv * 32 + 8 * g + 4 * hi]);
            short8 f0 = *(const short8*)(&A1[sw_idx(l31, hi)]);
            short8 f1 = *(const short8*)(&A1[sw_idx(l31 + 32, hi)]);
            a0 = __builtin_amdgcn_mfma_f32_32x32x16_bf16(w2f[0], f0, ci.v, 0, 0, 0);
            a1 = __builtin_amdgcn_mfma_f32_32x32x16_bf16(w2f[0], f1, ci.v, 0, 0, 0);
#pragma unroll
            for (int kc = 1; kc < 8; ++kc) {
                f0 = *(const short8*)(&A1[sw_idx(l31, kc * 2 + hi)]);
                f1 = *(const short8*)(&A1[sw_idx(l31 + 32, kc * 2 + hi)]);
                a0 = __builtin_amdgcn_mfma_f32_32x32x16_bf16(w2f[kc], f0, a0, 0, 0, 0);
                a1 = __builtin_amdgcn_mfma_f32_32x32x16_bf16(w2f[kc], f1, a1, 0, 0, 0);
            }
        }
        // consume previous tile's fused-L4 partials while MFMAs drain
        if (t > 0 && tid < MT) {
            int lr = (t - 1) * MT + tid;
            float u = posum[tid] + b4v;
            posum[tid] = 0.0f;
            if (lr < RPB) {
                unsigned mm = rowmap[lr];
                float dz = u > 0.0f ? u + 1.0f : __expf(u);  // elu(u)+1
                atomicAdd(&osum[mm >> 6], dz * fs[mm & 63]);
            }
        }
        // epilogue: relu(acc) -> A2 (bias already in acc)
#pragma unroll
        for (int g = 0; g < 4; ++g) {
            const int chI = wv * 4 + g;
            float v0 = fmaxf(a0[4 * g + 0], 0.0f), v1 = fmaxf(a0[4 * g + 1], 0.0f);
            float v2 = fmaxf(a0[4 * g + 2], 0.0f), v3 = fmaxf(a0[4 * g + 3], 0.0f);
            *(unsigned long long*)(&A2[sw_idx(l31, chI) + 4 * hi]) =
                ((unsigned long long)pk_bf16(v2, v3) << 32) | (unsigned long long)pk_bf16(v0, v1);
            v0 = fmaxf(a1[4 * g + 0], 0.0f); v1 = fmaxf(a1[4 * g + 1], 0.0f);
            v2 = fmaxf(a1[4 * g + 2], 0.0f); v3 = fmaxf(a1[4 * g + 3], 0.0f);
            *(unsigned long long*)(&A2[sw_idx(l31 + 32, chI) + 4 * hi]) =
                ((unsigned long long)pk_bf16(v2, v3) << 32) | (unsigned long long)pk_bf16(v0, v1);
        }
        __syncthreads();

        // ======== P2: layer 3 (read A2) + fused layer 4 + L1(t+1) ========
        floatx16 c0, c1;
        {
            union { floatx16 v; floatx4 q[4]; } ci;
#pragma unroll
            for (int g = 0; g < 4; ++g) ci.q[g] = *(const floatx4*)(&b3s[wv * 32 + 8 * g + 4 * hi]);
            short8 f0 = *(const short8*)(&A2[sw_idx(l31, hi)]);
            short8 f1 = *(const short8*)(&A2[sw_idx(l31 + 32, hi)]);
            c0 = __builtin_amdgcn_mfma_f32_32x32x16_bf16(w3f[0], f0, ci.v, 0, 0, 0);
            c1 = __builtin_amdgcn_mfma_f32_32x32x16_bf16(w3f[0], f1, ci.v, 0, 0, 0);
#pragma unroll
            for (int kc = 1; kc < 8; ++kc) {
                f0 = *(const short8*)(&A2[sw_idx(l31, kc * 2 + hi)]);
                f1 = *(const short8*)(&A2[sw_idx(l31 + 32, kc * 2 + hi)]);
                c0 = __builtin_amdgcn_mfma_f32_32x32x16_bf16(w3f[kc], f0, c0, 0, 0, 0);
                c1 = __builtin_amdgcn_mfma_f32_32x32x16_bf16(w3f[kc], f1, c1, 0, 0, 0);
            }
        }
        // fused layer 4: p[j] += sum_i relu(a3[i][j]) * w4[i] (bias pre-added in acc)
        {
            float p0 = 0.0f, p1 = 0.0f;
#pragma unroll
            for (int g = 0; g < 4; ++g) {
                const floatx4 w4v = *(const floatx4*)(&w4s[wv * 32 + 8 * g + 4 * hi]);
#pragma unroll
                for (int rr = 0; rr < 4; ++rr) {
                    p0 = fmaf(fmaxf(c0[4 * g + rr], 0.0f), w4v[rr], p0);
                    p1 = fmaf(fmaxf(c1[4 * g + rr], 0.0f), w4v[rr], p1);
                }
            }
            p0 += __shfl_xor(p0, 32);
            p1 += __shfl_xor(p1, 32);
            if (hi == 0) {
                atomicAdd(&posum[l31], p0);
                atomicAdd(&posum[l31 + 32], p1);
            }
        }
        // L1 for tile t+1 -> A1 (A1[t] fully consumed by P1's MFMAs before the barrier)
        if (t + 1 < NTILE) {
            int lr = (t + 1) * MT + r1;
            unsigned mm = rowmap[lr];
            unsigned bbl = mm >> 6;
            int ss = mm & 63;
            float X = xs[bbl] * ts[ss], hb = hs[bbl];
#pragma unroll
            for (int cc = 0; cc < 4; ++cc) {
                const int kc0 = (cb + cc) * 8;
                unsigned vv[4];
#pragma unroll
                for (int e2 = 0; e2 < 4; ++e2) {
                    float u0 = fmaxf(fmaf(X, w1s[kc0 + 2 * e2], fmaf(hb, w1s[HID + kc0 + 2 * e2], b1s[kc0 + 2 * e2])), 0.0f);
                    float u1 = fmaxf(fmaf(X, w1s[kc0 + 2 * e2 + 1], fmaf(hb, w1s[HID + kc0 + 2 * e2 + 1], b1s[kc0 + 2 * e2 + 1])), 0.0f);
                    vv[e2] = pk_bf16(u0, u1);
                }
                *(uint4*)(&A1[sw_idx(r1, cb + cc)]) = make_uint4(vv[0], vv[1], vv[2], vv[3]);
            }
        }
        __syncthreads();
    }

    // final consume of last tile's partials
    if (tid < MT) {
        int lr = (NTILE - 1) * MT + tid;
        if (lr < RPB) {
            float u = posum[tid] + b4v;
            unsigned mm = rowmap[lr];
            float dz = u > 0.0f ? u + 1.0f : __expf(u);
            atomicAdd(&osum[mm >> 6], dz * fs[mm & 63]);
        }
    }
    __syncthreads();

    if (tid < BPB) out[blockIdx.x * BPB + tid] = hs[tid] + osum[tid] * xs[tid];
}

extern "C" void kernel_launch(void* const* d_in, const int* in_sizes, int n_in,
                              void* d_out, int out_size, void* d_ws, size_t ws_size,
                              hipStream_t stream) {
    const float* x  = (const float*)d_in[0];
    const float* h  = (const float*)d_in[1];
    const float* w1 = (const float*)d_in[2];
    const float* b1 = (const float*)d_in[3];
    const float* w2 = (const float*)d_in[4];
    const float* b2 = (const float*)d_in[5];
    const float* w3 = (const float*)d_in[6];
    const float* b3 = (const float*)d_in[7];
    const float* w4 = (const float*)d_in[8];
    const float* b4 = (const float*)d_in[9];
    float* out = (float*)d_out;

    monotonic_fused<<<GRID, BLOCK, 0, stream>>>(x, h, w1, b1, w2, b2, w3, b3, w4, b4, out);
}

// Round 8
// 161.530 us; speedup vs baseline: 1.2746x; 1.0649x over previous
//
#include <hip/hip_runtime.h>
#include <hip/hip_bf16.h>

#define NSTEP 50
#define S51 51
#define HID 128
#define MT 64                  // rows per tile
#define BPB 16                 // batch elems per block (block owns them -> no global atomics)
#define RPB (BPB * S51)        // 816 valid rows per block
#define NTILE 13               // ceil(816/64): 832 rows, 16 masked (1.9% waste)
#define GRID (16384 / BPB)     // 1024 blocks = 4 per CU
#define BLOCK 256              // 4 waves

typedef __attribute__((ext_vector_type(8))) short short8;
typedef __attribute__((ext_vector_type(4))) float floatx4;
typedef __attribute__((ext_vector_type(16))) float floatx16;

// f32 pair -> packed bf16 (lowers to v_cvt_pk_bf16_f32 on gfx950; verified R5/R6)
__device__ __forceinline__ unsigned pk_bf16(float a, float b) {
#if __has_builtin(__builtin_amdgcn_cvt_pk_bf16_f32)
    typedef __bf16 bf16x2 __attribute__((ext_vector_type(2)));
    bf16x2 t = __builtin_amdgcn_cvt_pk_bf16_f32(a, b);   // D.lo = S0, D.hi = S1
    unsigned u;
    __builtin_memcpy(&u, &t, 4);
    return u;
#else
    unsigned ua = __float_as_uint(a), ub = __float_as_uint(b);
    ua = ua + 0x7fffu + ((ua >> 16) & 1u);
    ub = ub + 0x7fffu + ((ub >> 16) & 1u);
    return __builtin_amdgcn_perm(ub, ua, 0x07060302);    // [ua.hi16, ub.hi16]
#endif
}

// Swizzled activation layout: row-major 64x128 bf16, rows = 16 chunks of 16B,
// phys_chunk = chunk ^ (row & 15).
__device__ __forceinline__ int sw_idx(int row, int chunk) {
    return row * HID + ((chunk ^ (row & 15)) << 3);   // in shorts
}

// Register-only C-operand build (R7's union variant spilled: 27.7 MB scratch writes)
__device__ __forceinline__ floatx16 ld_bias16(const float* bs, int base) {
    const floatx4 t0 = *(const floatx4*)(&bs[base]);
    const floatx4 t1 = *(const floatx4*)(&bs[base + 8]);
    const floatx4 t2 = *(const floatx4*)(&bs[base + 16]);
    const floatx4 t3 = *(const floatx4*)(&bs[base + 24]);
    floatx16 v = {t0[0], t0[1], t0[2], t0[3], t1[0], t1[1], t1[2], t1[3],
                  t2[0], t2[1], t2[2], t2[3], t3[0], t3[1], t3[2], t3[3]};
    return v;
}

// R7 structure + (1) spill-free C-operand bias  (2) posum atomics -> per-wave
// plain stores (posum4).  4 waves/block; wave wv owns hidden slice
// [wv*32, wv*32+32) as MFMA A-operand (W^T in regs). L4 fused into L3 accs.
__launch_bounds__(BLOCK, 4)
__global__ void monotonic_fused(const float* __restrict__ x, const float* __restrict__ h,
                                const float* __restrict__ w1, const float* __restrict__ b1,
                                const float* __restrict__ w2, const float* __restrict__ b2,
                                const float* __restrict__ w3, const float* __restrict__ b3,
                                const float* __restrict__ w4, const float* __restrict__ b4,
                                float* __restrict__ out) {
    __shared__ __align__(16) unsigned short A1[MT * HID];   // a1 (L1 out, L2 in), 16 KB
    __shared__ __align__(16) unsigned short A2[MT * HID];   // a2 (L2 out, L3 in), 16 KB
    __shared__ float w1s[2 * HID], b1s[HID], b2s[HID], b3s[HID], w4s[HID];
    __shared__ float fs[S51], ts[S51];
    __shared__ float xs[BPB], hs[BPB], osum[BPB];
    __shared__ float posum4[4][MT];                          // per-wave fused-L4 partials
    __shared__ unsigned short rowmap[NTILE * MT];            // (bbl<<6)|ss per row

    const int tid = threadIdx.x;
    const int lane = tid & 63;
    const int wv = tid >> 6;      // 0..3 = hidden 32-slice
    const int l31 = lane & 31;
    const int hi = lane >> 5;
    const int r1 = tid >> 2;          // L1 writer: row 0..63
    const int cb = (tid & 3) * 4;     // L1 writer: base chunk (4 chunks = 32 k-cols)

    // ---- stage small tensors ----
    w1s[tid] = w1[tid];               // 256 threads = 256 elems exactly
    if (tid < HID) {
        b1s[tid] = b1[tid]; b2s[tid] = b2[tid]; b3s[tid] = b3[tid]; w4s[tid] = w4[tid];
    }
    if (tid < BPB) {
        xs[tid] = x[blockIdx.x * BPB + tid];
        hs[tid] = h[blockIdx.x * BPB + tid];
        osum[tid] = 0.0f;
    }
    for (int i = tid; i < NTILE * MT; i += BLOCK) {
        int lrc = i < RPB ? i : RPB - 1;
        unsigned bbl = (unsigned)lrc / 51u;
        int ss = lrc - (int)bbl * 51;
        rowmap[i] = (unsigned short)((bbl << 6) | ss);
    }
    if (tid < S51) {
        // Faithful port of compute_cc_weights (verified R1-R7, absmax 0.031)
        const float PI50 = 0.06283185307179586f;  // pi/50
        float acc = 1.0f;
        for (int i = 2; i <= 50; i += 2) {
            int m = (i * tid) % 100;  // exact argument reduction
            acc += (2.0f / (1.0f - (float)(i * i))) * cosf((float)m * PI50);
        }
        float ccw = acc * 0.04f * ((tid == 0 || tid == NSTEP) ? 0.5f : 1.0f);
        fs[tid] = ccw * 0.5f;                               // folds the (x-x0)*0.5 factor
        ts[tid] = (cosf((float)tid * PI50) + 1.0f) * 0.5f;  // (steps+1)/2
    }
    const float b4v = b4[0];

    // ---- gather W2^T / W3^T A-operand fragments (coalesced over l31) ----
    // frag[kc] elem e = W[kc*16 + hi*8 + e][wv*32 + l31]
    short8 w2f[8], w3f[8];
    {
        const int irow = wv * 32 + l31;
#pragma unroll
        for (int kc = 0; kc < 8; ++kc) {
            const int kb = kc * 16 + hi * 8;
            union { short8 s; unsigned u[4]; } c2, c3;
#pragma unroll
            for (int e2 = 0; e2 < 4; ++e2) {
                c2.u[e2] = pk_bf16(w2[(kb + 2 * e2) * HID + irow], w2[(kb + 2 * e2 + 1) * HID + irow]);
                c3.u[e2] = pk_bf16(w3[(kb + 2 * e2) * HID + irow], w3[(kb + 2 * e2 + 1) * HID + irow]);
            }
            w2f[kc] = c2.s;
            w3f[kc] = c3.s;
        }
    }
    __syncthreads();

    // ---- L1 for tile 0 -> A1 ----
    {
        unsigned mm = rowmap[r1];
        unsigned bbl = mm >> 6;
        int ss = mm & 63;
        float X = xs[bbl] * ts[ss], hb = hs[bbl];
#pragma unroll
        for (int cc = 0; cc < 4; ++cc) {
            const int kc0 = (cb + cc) * 8;
            unsigned vv[4];
#pragma unroll
            for (int e2 = 0; e2 < 4; ++e2) {
                float u0 = fmaxf(fmaf(X, w1s[kc0 + 2 * e2], fmaf(hb, w1s[HID + kc0 + 2 * e2], b1s[kc0 + 2 * e2])), 0.0f);
                float u1 = fmaxf(fmaf(X, w1s[kc0 + 2 * e2 + 1], fmaf(hb, w1s[HID + kc0 + 2 * e2 + 1], b1s[kc0 + 2 * e2 + 1])), 0.0f);
                vv[e2] = pk_bf16(u0, u1);
            }
            *(uint4*)(&A1[sw_idx(r1, cb + cc)]) = make_uint4(vv[0], vv[1], vv[2], vv[3]);
        }
    }
    __syncthreads();

    for (int t = 0; t < NTILE; ++t) {
        // ======== P1: layer 2 (read A1); bias enters as C of the peeled MFMA ========
        floatx16 a0, a1;
        {
            const floatx16 ci = ld_bias16(b2s, wv * 32 + 4 * hi);
            short8 f0 = *(const short8*)(&A1[sw_idx(l31, hi)]);
            short8 f1 = *(const short8*)(&A1[sw_idx(l31 + 32, hi)]);
            a0 = __builtin_amdgcn_mfma_f32_32x32x16_bf16(w2f[0], f0, ci, 0, 0, 0);
            a1 = __builtin_amdgcn_mfma_f32_32x32x16_bf16(w2f[0], f1, ci, 0, 0, 0);
#pragma unroll
            for (int kc = 1; kc < 8; ++kc) {
                f0 = *(const short8*)(&A1[sw_idx(l31, kc * 2 + hi)]);
                f1 = *(const short8*)(&A1[sw_idx(l31 + 32, kc * 2 + hi)]);
                a0 = __builtin_amdgcn_mfma_f32_32x32x16_bf16(w2f[kc], f0, a0, 0, 0, 0);
                a1 = __builtin_amdgcn_mfma_f32_32x32x16_bf16(w2f[kc], f1, a1, 0, 0, 0);
            }
        }
        // consume previous tile's fused-L4 partials while MFMAs drain
        if (t > 0 && tid < MT) {
            int lr = (t - 1) * MT + tid;
            float u = posum4[0][tid] + posum4[1][tid] + posum4[2][tid] + posum4[3][tid] + b4v;
            if (lr < RPB) {
                unsigned mm = rowmap[lr];
                float dz = u > 0.0f ? u + 1.0f : __expf(u);  // elu(u)+1
                atomicAdd(&osum[mm >> 6], dz * fs[mm & 63]);
            }
        }
        // epilogue: relu(acc) -> A2 (bias already in acc)
#pragma unroll
        for (int g = 0; g < 4; ++g) {
            const int chI = wv * 4 + g;
            float v0 = fmaxf(a0[4 * g + 0], 0.0f), v1 = fmaxf(a0[4 * g + 1], 0.0f);
            float v2 = fmaxf(a0[4 * g + 2], 0.0f), v3 = fmaxf(a0[4 * g + 3], 0.0f);
            *(unsigned long long*)(&A2[sw_idx(l31, chI) + 4 * hi]) =
                ((unsigned long long)pk_bf16(v2, v3) << 32) | (unsigned long long)pk_bf16(v0, v1);
            v0 = fmaxf(a1[4 * g + 0], 0.0f); v1 = fmaxf(a1[4 * g + 1], 0.0f);
            v2 = fmaxf(a1[4 * g + 2], 0.0f); v3 = fmaxf(a1[4 * g + 3], 0.0f);
            *(unsigned long long*)(&A2[sw_idx(l31 + 32, chI) + 4 * hi]) =
                ((unsigned long long)pk_bf16(v2, v3) << 32) | (unsigned long long)pk_bf16(v0, v1);
        }
        __syncthreads();

        // ======== P2: layer 3 (read A2) + fused layer 4 + L1(t+1) ========
        floatx16 c0, c1;
        {
            const floatx16 ci = ld_bias16(b3s, wv * 32 + 4 * hi);
            short8 f0 = *(const short8*)(&A2[sw_idx(l31, hi)]);
            short8 f1 = *(const short8*)(&A2[sw_idx(l31 + 32, hi)]);
            c0 = __builtin_amdgcn_mfma_f32_32x32x16_bf16(w3f[0], f0, ci, 0, 0, 0);
            c1 = __builtin_amdgcn_mfma_f32_32x32x16_bf16(w3f[0], f1, ci, 0, 0, 0);
#pragma unroll
            for (int kc = 1; kc < 8; ++kc) {
                f0 = *(const short8*)(&A2[sw_idx(l31, kc * 2 + hi)]);
                f1 = *(const short8*)(&A2[sw_idx(l31 + 32, kc * 2 + hi)]);
                c0 = __builtin_amdgcn_mfma_f32_32x32x16_bf16(w3f[kc], f0, c0, 0, 0, 0);
                c1 = __builtin_amdgcn_mfma_f32_32x32x16_bf16(w3f[kc], f1, c1, 0, 0, 0);
            }
        }
        // fused layer 4: per-wave partials, plain stores (no LDS atomics)
        {
            float p0 = 0.0f, p1 = 0.0f;
#pragma unroll
            for (int g = 0; g < 4; ++g) {
                const floatx4 w4v = *(const floatx4*)(&w4s[wv * 32 + 8 * g + 4 * hi]);
#pragma unroll
                for (int rr = 0; rr < 4; ++rr) {
                    p0 = fmaf(fmaxf(c0[4 * g + rr], 0.0f), w4v[rr], p0);
                    p1 = fmaf(fmaxf(c1[4 * g + rr], 0.0f), w4v[rr], p1);
                }
            }
            p0 += __shfl_xor(p0, 32);
            p1 += __shfl_xor(p1, 32);
            if (hi == 0) {
                posum4[wv][l31] = p0;
                posum4[wv][l31 + 32] = p1;
            }
        }
        // L1 for tile t+1 -> A1 (A1[t] fully consumed by P1's MFMAs before the barrier)
        if (t + 1 < NTILE) {
            int lr = (t + 1) * MT + r1;
            unsigned mm = rowmap[lr];
            unsigned bbl = mm >> 6;
            int ss = mm & 63;
            float X = xs[bbl] * ts[ss], hb = hs[bbl];
#pragma unroll
            for (int cc = 0; cc < 4; ++cc) {
                const int kc0 = (cb + cc) * 8;
                unsigned vv[4];
#pragma unroll
                for (int e2 = 0; e2 < 4; ++e2) {
                    float u0 = fmaxf(fmaf(X, w1s[kc0 + 2 * e2], fmaf(hb, w1s[HID + kc0 + 2 * e2], b1s[kc0 + 2 * e2])), 0.0f);
                    float u1 = fmaxf(fmaf(X, w1s[kc0 + 2 * e2 + 1], fmaf(hb, w1s[HID + kc0 + 2 * e2 + 1], b1s[kc0 + 2 * e2 + 1])), 0.0f);
                    vv[e2] = pk_bf16(u0, u1);
                }
                *(uint4*)(&A1[sw_idx(r1, cb + cc)]) = make_uint4(vv[0], vv[1], vv[2], vv[3]);
            }
        }
        __syncthreads();
    }

    // final consume of last tile's partials
    if (tid < MT) {
        int lr = (NTILE - 1) * MT + tid;
        if (lr < RPB) {
            float u = posum4[0][tid] + posum4[1][tid] + posum4[2][tid] + posum4[3][tid] + b4v;
            unsigned mm = rowmap[lr];
            float dz = u > 0.0f ? u + 1.0f : __expf(u);
            atomicAdd(&osum[mm >> 6], dz * fs[mm & 63]);
        }
    }
    __syncthreads();

    if (tid < BPB) out[blockIdx.x * BPB + tid] = hs[tid] + osum[tid] * xs[tid];
}

extern "C" void kernel_launch(void* const* d_in, const int* in_sizes, int n_in,
                              void* d_out, int out_size, void* d_ws, size_t ws_size,
                              hipStream_t stream) {
    const float* x  = (const float*)d_in[0];
    const float* h  = (const float*)d_in[1];
    const float* w1 = (const float*)d_in[2];
    const float* b1 = (const float*)d_in[3];
    const float* w2 = (const float*)d_in[4];
    const float* b2 = (const float*)d_in[5];
    const float* w3 = (const float*)d_in[6];
    const float* b3 = (const float*)d_in[7];
    const float* w4 = (const float*)d_in[8];
    const float* b4 = (const float*)d_in[9];
    float* out = (float*)d_out;

    monotonic_fused<<<GRID, BLOCK, 0, stream>>>(x, h, w1, b1, w2, b2, w3, b3, w4, b4, out);
}